// Round 3
// baseline (2113.246 us; speedup 1.0000x reference)
//
#include <hip/hip_runtime.h>
#include <math.h>

#define HD 64   // H == F == 64
#define GD 50   // num gaussians
#define HALF 32 // half of HD: LDS row width (floats) for scatter passes
#define PAD 36  // LDS row stride in floats: 144B, 16B-aligned, mod32==4 -> b128 spread
#define EPW 64
#define WPB 2

__device__ __forceinline__ float ssp_f(float x) {
    // shifted softplus: softplus(x) - ln2, stable form max(x,0)+log(1+exp(-|x|))
    float ax = __builtin_fabsf(x);
    float e  = __expf(-ax);
    float sp = fmaxf(x, 0.0f) + __logf(1.0f + e);
    return sp - 0.69314718055994531f;
}

// xs = x @ l1w : [N,64]; also zero agg. gridDim.y selects edge-type t.
__global__ void __launch_bounds__(256) xs_kernel(
        const float* __restrict__ xA, const float* __restrict__ xB,
        const float* __restrict__ wA, const float* __restrict__ wB,
        float* __restrict__ xsA, float* __restrict__ xsB,
        float* __restrict__ aggA, float* __restrict__ aggB,
        int NA, int NB) {
    const int t = blockIdx.y;
    const float* x   = t ? xB : xA;
    const float* w   = t ? wB : wA;
    float* xs  = t ? xsB : xsA;
    float* agg = t ? aggB : aggA;
    const int N = t ? NB : NA;

    int wv = threadIdx.x >> 6;
    int j  = threadIdx.x & 63;
    int n  = blockIdx.x * 4 + wv;
    __shared__ float xr[4][64];
    if (n < N) xr[wv][j] = x[(size_t)n * HD + j];
    __syncthreads();
    if (n >= N) return;
    float acc = 0.0f;
#pragma unroll
    for (int k = 0; k < HD; ++k)
        acc = fmaf(xr[wv][k], w[k * HD + j], acc);
    xs[(size_t)n * HD + j] = acc;
    agg[(size_t)n * HD + j] = 0.0f;
}

// Per-edge filter MLP + modulate + scatter. Register-clean restructure:
//   ea row resident in VGPRs (25 float2, one vmcnt wait; last 2 parked in the
//   4 spare floats of the PAD=36 LDS row). h computed in chunks of 4 and
//   immediately folded into w[64] (separable over g), so h[64] is never live.
//   Peak VGPR ~120 (re46 + w64 + h4 + temps) -> no spills at the 128 cap
//   (launch_bounds(128,4): 4 waves/EU, matches the 8-block LDS cap).
//   All weight reads are wave-uniform -> SGPR operands, zero VGPR cost.
//   Scatter: two 32-channel passes, xs upper half stashed in 32 VGPRs in
//   pass 0 (full-unroll -> static indexing). gridDim.y selects edge type.
__global__ void __launch_bounds__(WPB * 64, 4) edge_kernel(
        const float* __restrict__ eaA, const float* __restrict__ eaB,
        const float* __restrict__ ewA, const float* __restrict__ ewB,
        const int* __restrict__ eiA, const int* __restrict__ eiB,
        const float* __restrict__ xsA, const float* __restrict__ xsB,
        float* __restrict__ aggA, float* __restrict__ aggB,
        const float* __restrict__ mw1, const float* __restrict__ mb1,
        const float* __restrict__ mw2, const float* __restrict__ mb2,
        int EA, int EB) {
    const int t = blockIdx.y;
    const float* ea = t ? eaB : eaA;
    const float* ew = t ? ewB : ewA;
    const int*   ei = t ? eiB : eiA;
    const float* xs = t ? xsB : xsA;
    float*      agg = t ? aggB : aggA;
    const int E = t ? EB : EA;

    if ((size_t)blockIdx.x * (WPB * EPW) >= (size_t)E) return;  // whole-block guard

    const int wv   = threadIdx.x >> 6;
    const int lane = threadIdx.x & 63;
    const int ebase = (blockIdx.x * WPB + wv) * EPW;

    __shared__ float wbuf[WPB][EPW * PAD];
    __shared__ int   sdst[WPB][EPW];
    __shared__ int   ssrc[WPB][EPW];

    int e = ebase + lane;
    bool valid = e < E;
    int ec = valid ? e : E - 1;

    // early: indices straight to LDS (own slot, pre-barrier), cutoff folded now
    sdst[wv][lane] = ei[(size_t)E + ec];
    ssrc[wv][lane] = ei[ec];
    float cw = 0.5f * (__cosf(ew[ec] * 0.31415926535897931f) + 1.0f);
    if (!valid) cw = 0.0f;

    // ---- ea row resident: 23 float2 in regs, last 2 parked in LDS spare ----
    const float2* ear2 = (const float2*)(ea + (size_t)ec * GD);
    float2 re[23];
#pragma unroll
    for (int g = 0; g < 23; ++g) re[g] = ear2[g];
    float2 rt0 = ear2[23], rt1 = ear2[24];
    float* hrow = &wbuf[wv][lane * PAD];
    *(float4*)(hrow + HALF) = make_float4(rt0.x, rt0.y, rt1.x, rt1.y);  // own row, no barrier

    // ---- fused MLP: h in chunks of 4, folded into w[64] immediately ----
    float w[HD];
#pragma unroll
    for (int j = 0; j < HD; ++j) w[j] = mb2[j];

#pragma unroll 2
    for (int cb = 0; cb < HD / 4; ++cb) {       // 16 chunks
        const int c0 = 4 * cb;
        float h0 = mb1[c0], h1 = mb1[c0 + 1], h2 = mb1[c0 + 2], h3 = mb1[c0 + 3];
#pragma unroll
        for (int g = 0; g < 23; ++g) {
            const float* w0 = mw1 + (2 * g) * HD + c0;   // uniform -> s_load
            h0 = fmaf(re[g].x, w0[0], h0);
            h1 = fmaf(re[g].x, w0[1], h1);
            h2 = fmaf(re[g].x, w0[2], h2);
            h3 = fmaf(re[g].x, w0[3], h3);
            h0 = fmaf(re[g].y, w0[HD],     h0);
            h1 = fmaf(re[g].y, w0[HD + 1], h1);
            h2 = fmaf(re[g].y, w0[HD + 2], h2);
            h3 = fmaf(re[g].y, w0[HD + 3], h3);
        }
        {   // parked tail: g = 46..49
            float4 rt = *(const float4*)(hrow + HALF);
            const float* w0 = mw1 + 46 * HD + c0;
            h0 = fmaf(rt.x, w0[0], h0); h1 = fmaf(rt.x, w0[1], h1);
            h2 = fmaf(rt.x, w0[2], h2); h3 = fmaf(rt.x, w0[3], h3);
            h0 = fmaf(rt.y, w0[HD],     h0); h1 = fmaf(rt.y, w0[HD + 1], h1);
            h2 = fmaf(rt.y, w0[HD + 2], h2); h3 = fmaf(rt.y, w0[HD + 3], h3);
            h0 = fmaf(rt.z, w0[2*HD],     h0); h1 = fmaf(rt.z, w0[2*HD + 1], h1);
            h2 = fmaf(rt.z, w0[2*HD + 2], h2); h3 = fmaf(rt.z, w0[2*HD + 3], h3);
            h0 = fmaf(rt.w, w0[3*HD],     h0); h1 = fmaf(rt.w, w0[3*HD + 1], h1);
            h2 = fmaf(rt.w, w0[3*HD + 2], h2); h3 = fmaf(rt.w, w0[3*HD + 3], h3);
        }
        float s0 = ssp_f(h0), s1 = ssp_f(h1), s2 = ssp_f(h2), s3 = ssp_f(h3);
        const float* r0 = mw2 + c0 * HD;                 // uniform -> s_load
#pragma unroll
        for (int j = 0; j < HD; ++j) w[j] = fmaf(s0, r0[j], w[j]);
#pragma unroll
        for (int j = 0; j < HD; ++j) w[j] = fmaf(s1, r0[HD + j], w[j]);
#pragma unroll
        for (int j = 0; j < HD; ++j) w[j] = fmaf(s2, r0[2 * HD + j], w[j]);
#pragma unroll
        for (int j = 0; j < HD; ++j) w[j] = fmaf(s3, r0[3 * HD + j], w[j]);
    }

    const int c  = lane & 31;   // channel within half
    const int eh = lane & 32;   // which edge half this lane handles

    // ---- pass 0: channels [0,32); stash upper xs half in VGPRs ----
#pragma unroll
    for (int q = 0; q < HALF / 4; ++q)
        *(float4*)(hrow + 4 * q) = make_float4(w[4*q] * cw,     w[4*q + 1] * cw,
                                               w[4*q + 2] * cw, w[4*q + 3] * cw);
    __syncthreads();
    float xh[EPW / 2];   // statically indexed (full unroll) -> VGPRs
#pragma unroll
    for (int k = 0; k < EPW / 2; ++k) {
        int idx = k + eh;
        int dst = sdst[wv][idx];
        int src = ssrc[wv][idx];
        const float* xp = xs + (size_t)src * HD + c;
        float xlo = xp[0];
        xh[k] = xp[HALF];
        atomicAdd(&agg[(size_t)dst * HD + c], xlo * wbuf[wv][idx * PAD + c]);
    }
    __syncthreads();   // all lanes done reading before overwrite

    // ---- pass 1: channels [32,64); zero global reads ----
#pragma unroll
    for (int q = 0; q < HALF / 4; ++q)
        *(float4*)(hrow + 4 * q) = make_float4(w[HALF + 4*q] * cw,     w[HALF + 4*q + 1] * cw,
                                               w[HALF + 4*q + 2] * cw, w[HALF + 4*q + 3] * cw);
    __syncthreads();
#pragma unroll
    for (int k = 0; k < EPW / 2; ++k) {
        int idx = k + eh;
        int dst = sdst[wv][idx];
        atomicAdd(&agg[(size_t)dst * HD + HALF + c], xh[k] * wbuf[wv][idx * PAD + c]);
    }
}

// out = ssp(agg @ l2w + l2b) @ lin_w + lin_b. gridDim.y selects edge type.
__global__ void __launch_bounds__(256) out_kernel(
        const float* __restrict__ aggA, const float* __restrict__ aggB,
        const float* __restrict__ l2wA, const float* __restrict__ l2wB,
        const float* __restrict__ l2bA, const float* __restrict__ l2bB,
        const float* __restrict__ lw, const float* __restrict__ lb,
        float* __restrict__ outA, float* __restrict__ outB,
        int NA, int NB) {
    const int t = blockIdx.y;
    const float* agg = t ? aggB : aggA;
    const float* l2w = t ? l2wB : l2wA;
    const float* l2b = t ? l2bB : l2bA;
    float* out = t ? outB : outA;
    const int N = t ? NB : NA;

    int wv = threadIdx.x >> 6;
    int j  = threadIdx.x & 63;
    int n  = blockIdx.x * 4 + wv;
    __shared__ float buf[4][64];
    bool ok = n < N;
    if (ok) buf[wv][j] = agg[(size_t)n * HD + j];
    __syncthreads();
    float h = l2b[j];
#pragma unroll
    for (int g = 0; g < HD; ++g)
        h = fmaf(buf[wv][g], l2w[g * HD + j], h);
    h = ssp_f(h);
    __syncthreads();
    buf[wv][j] = h;
    __syncthreads();
    float o = lb[j];
#pragma unroll
    for (int g = 0; g < HD; ++g)
        o = fmaf(buf[wv][g], lw[g * HD + j], o);
    if (ok) out[(size_t)n * HD + j] = o;
}

extern "C" void kernel_launch(void* const* d_in, const int* in_sizes, int n_in,
                              void* d_out, int out_size, void* d_ws, size_t ws_size,
                              hipStream_t stream) {
    const float* x0   = (const float*)d_in[0];
    const float* x1   = (const float*)d_in[1];
    const int*   ei0  = (const int*)d_in[2];
    const int*   ei1  = (const int*)d_in[3];
    const float* ew0  = (const float*)d_in[4];
    const float* ew1  = (const float*)d_in[5];
    const float* ea0  = (const float*)d_in[6];
    const float* ea1  = (const float*)d_in[7];
    const float* mw1  = (const float*)d_in[8];
    const float* mb1  = (const float*)d_in[9];
    const float* mw2  = (const float*)d_in[10];
    const float* mb2  = (const float*)d_in[11];
    const float* l1w0 = (const float*)d_in[12];
    const float* l2w0 = (const float*)d_in[13];
    const float* l2b0 = (const float*)d_in[14];
    const float* l1w1 = (const float*)d_in[15];
    const float* l2w1 = (const float*)d_in[16];
    const float* l2b1 = (const float*)d_in[17];
    const float* lw   = (const float*)d_in[18];
    const float* lb   = (const float*)d_in[19];

    int N0 = in_sizes[0] / HD;
    int N1 = in_sizes[1] / HD;
    int E0 = in_sizes[4];
    int E1 = in_sizes[5];
    float* out = (float*)d_out;
    float* out0 = out;
    float* out1 = out + (size_t)N0 * HD;

    int Nmax = N0 > N1 ? N0 : N1;
    int Emax = E0 > E1 ? E0 : E1;
    int nodeBlocks = (Nmax + 3) / 4;
    int edgeBlocks = (Emax + WPB * EPW - 1) / (WPB * EPW);

    size_t needMerged = (size_t)(N0 + N1) * HD * 2 * sizeof(float);

    if (ws_size >= needMerged) {
        // merged path: 3 dispatches, gridDim.y = 2
        float* xs0  = (float*)d_ws;
        float* xs1  = xs0 + (size_t)N0 * HD;
        float* agg0 = xs1 + (size_t)N1 * HD;
        float* agg1 = agg0 + (size_t)N0 * HD;

        xs_kernel<<<dim3(nodeBlocks, 2), 256, 0, stream>>>(
            x0, x1, l1w0, l1w1, xs0, xs1, agg0, agg1, N0, N1);
        edge_kernel<<<dim3(edgeBlocks, 2), WPB * 64, 0, stream>>>(
            ea0, ea1, ew0, ew1, ei0, ei1, xs0, xs1, agg0, agg1,
            mw1, mb1, mw2, mb2, E0, E1);
        out_kernel<<<dim3(nodeBlocks, 2), 256, 0, stream>>>(
            agg0, agg1, l2w0, l2w1, l2b0, l2b1, lw, lb, out0, out1, N0, N1);
    } else {
        // fallback: sequential t-loop sharing one xs/agg buffer
        float* xs  = (float*)d_ws;
        float* agg = xs + (size_t)Nmax * HD;
        for (int t = 0; t < 2; ++t) {
            const float* x   = t ? x1 : x0;
            const int*   ei  = t ? ei1 : ei0;
            const float* ewp = t ? ew1 : ew0;
            const float* eap = t ? ea1 : ea0;
            const float* l1w = t ? l1w1 : l1w0;
            const float* l2w = t ? l2w1 : l2w0;
            const float* l2b = t ? l2b1 : l2b0;
            int N = t ? N1 : N0;
            int E = t ? E1 : E0;
            float* outp = t ? out1 : out0;
            int nb = (N + 3) / 4;
            int eb = (E + WPB * EPW - 1) / (WPB * EPW);
            xs_kernel<<<dim3(nb, 1), 256, 0, stream>>>(
                x, x, l1w, l1w, xs, xs, agg, agg, N, N);
            edge_kernel<<<dim3(eb, 1), WPB * 64, 0, stream>>>(
                eap, eap, ewp, ewp, ei, ei, xs, xs, agg, agg,
                mw1, mb1, mw2, mb2, E, E);
            out_kernel<<<dim3(nb, 1), 256, 0, stream>>>(
                agg, agg, l2w, l2w, l2b, l2b, lw, lb, outp, outp, N, N);
        }
    }
}

// Round 5
// 1189.212 us; speedup vs baseline: 1.7770x; 1.7770x over previous
//
#include <hip/hip_runtime.h>
#include <math.h>

#define HD 64   // H == F == 64
#define GD 50   // num gaussians
#define HALF 32 // half of HD: LDS row width (floats) for scatter passes
#define PAD 36  // LDS row stride in floats: 144B, 16B-aligned, mod32==4 -> b128 spread
#define EPW 64
#define WPB 2

__device__ __forceinline__ float ssp_f(float x) {
    // shifted softplus: softplus(x) - ln2, stable form max(x,0)+log(1+exp(-|x|))
    float ax = __builtin_fabsf(x);
    float e  = __expf(-ax);
    float sp = fmaxf(x, 0.0f) + __logf(1.0f + e);
    return sp - 0.69314718055994531f;
}

// xs = x @ l1w : [N,64]; also zero agg. gridDim.y selects edge-type t.
__global__ void __launch_bounds__(256) xs_kernel(
        const float* __restrict__ xA, const float* __restrict__ xB,
        const float* __restrict__ wA, const float* __restrict__ wB,
        float* __restrict__ xsA, float* __restrict__ xsB,
        float* __restrict__ aggA, float* __restrict__ aggB,
        int NA, int NB) {
    const int t = blockIdx.y;
    const float* x   = t ? xB : xA;
    const float* w   = t ? wB : wA;
    float* xs  = t ? xsB : xsA;
    float* agg = t ? aggB : aggA;
    const int N = t ? NB : NA;

    int wv = threadIdx.x >> 6;
    int j  = threadIdx.x & 63;
    int n  = blockIdx.x * 4 + wv;
    __shared__ float xr[4][64];
    if (n < N) xr[wv][j] = x[(size_t)n * HD + j];
    __syncthreads();
    if (n >= N) return;
    float acc = 0.0f;
#pragma unroll
    for (int k = 0; k < HD; ++k)
        acc = fmaf(xr[wv][k], w[k * HD + j], acc);
    xs[(size_t)n * HD + j] = acc;
    agg[(size_t)n * HD + j] = 0.0f;
}

// Per-edge filter MLP + modulate + scatter. R2 structure (sequential liveness:
//   h[64] -> park h_hi -> w[64]); the ONLY change vs R2 is launch_bounds(128,2)
//   to unpin the register allocator (empirically (,4) pins VGPR=64 and forces
//   AGPR/scratch shuffling of the ~100-live-value phases; (,2) gave 88 in R0
//   with zero scratch). LDS 19456B still caps residency at 8 blocks/CU = 16
//   waves = 4 waves/EU, so occupancy is unchanged while VGPR <= 128.
//   gridDim.y selects edge type (merged dispatch).
__global__ void __launch_bounds__(WPB * 64, 2) edge_kernel(
        const float* __restrict__ eaA, const float* __restrict__ eaB,
        const float* __restrict__ ewA, const float* __restrict__ ewB,
        const int* __restrict__ eiA, const int* __restrict__ eiB,
        const float* __restrict__ xsA, const float* __restrict__ xsB,
        float* __restrict__ aggA, float* __restrict__ aggB,
        const float* __restrict__ mw1, const float* __restrict__ mb1,
        const float* __restrict__ mw2, const float* __restrict__ mb2,
        int EA, int EB) {
    const int t = blockIdx.y;
    const float* ea = t ? eaB : eaA;
    const float* ew = t ? ewB : ewA;
    const int*   ei = t ? eiB : eiA;
    const float* xs = t ? xsB : xsA;
    float*      agg = t ? aggB : aggA;
    const int E = t ? EB : EA;

    if ((size_t)blockIdx.x * (WPB * EPW) >= (size_t)E) return;  // whole-block guard

    const int wv   = threadIdx.x >> 6;
    const int lane = threadIdx.x & 63;
    const long ebase = ((long)blockIdx.x * WPB + wv) * EPW;

    __shared__ float wbuf[WPB][EPW * PAD];
    __shared__ int   sdst[WPB][EPW];
    __shared__ int   ssrc[WPB][EPW];

    long e = ebase + lane;
    bool valid = e < (long)E;
    long ec = valid ? e : (long)E - 1;

    // ---- layer 1: h = ea_row @ mw1 + mb1 (h static-indexed -> VGPRs) ----
    const float2* ear2 = (const float2*)(ea + ec * GD);
    float h[HD];
#pragma unroll
    for (int f = 0; f < HD; ++f) h[f] = mb1[f];
    {
        float2 v = ear2[0];
        for (int gc = 0; gc < GD / 2; ++gc) {   // 25 iters; next load hidden under FMAs
            int gn = gc + 1 < GD / 2 ? gc + 1 : GD / 2 - 1;
            float2 vn = ear2[gn];
            const float* wr = mw1 + 2 * gc * HD;
#pragma unroll
            for (int f = 0; f < HD; ++f) h[f] = fmaf(v.x, wr[f], h[f]);
#pragma unroll
            for (int f = 0; f < HD; ++f) h[f] = fmaf(v.y, wr[HD + f], h[f]);
            v = vn;
        }
    }

    // ---- park upper half of h (raw) in own LDS row: 32 floats, b128 stores ----
    float* hrow = &wbuf[wv][lane * PAD];
#pragma unroll
    for (int q = 0; q < HALF / 4; ++q)
        *(float4*)(hrow + 4 * q) = make_float4(h[HALF + 4*q],     h[HALF + 4*q + 1],
                                               h[HALF + 4*q + 2], h[HALF + 4*q + 3]);

    float w[HD];
#pragma unroll
    for (int j = 0; j < HD; ++j) w[j] = mb2[j];

    // ---- layer 2 part A: g in [0,32) from registers (fully unrolled) ----
#pragma unroll
    for (int gb = 0; gb < HALF / 4; ++gb) {
        float s0 = ssp_f(h[4*gb + 0]);
        float s1 = ssp_f(h[4*gb + 1]);
        float s2 = ssp_f(h[4*gb + 2]);
        float s3 = ssp_f(h[4*gb + 3]);
        const float* wr = mw2 + 4 * gb * HD;
#pragma unroll
        for (int j = 0; j < HD; ++j) w[j] = fmaf(s0, wr[j], w[j]);
#pragma unroll
        for (int j = 0; j < HD; ++j) w[j] = fmaf(s1, wr[HD + j], w[j]);
#pragma unroll
        for (int j = 0; j < HD; ++j) w[j] = fmaf(s2, wr[2 * HD + j], w[j]);
#pragma unroll
        for (int j = 0; j < HD; ++j) w[j] = fmaf(s3, wr[3 * HD + j], w[j]);
    }

    // ---- layer 2 part B: g in [32,64) from LDS (prefetched b128 reads) ----
    {
        float4 hv = *(const float4*)(hrow);
        for (int gb = 0; gb < HALF / 4; ++gb) {
            int gn = gb + 1 < HALF / 4 ? gb + 1 : HALF / 4 - 1;
            float4 hn = *(const float4*)(hrow + 4 * gn);
            float s0 = ssp_f(hv.x), s1 = ssp_f(hv.y), s2 = ssp_f(hv.z), s3 = ssp_f(hv.w);
            const float* wr = mw2 + (HALF + 4 * gb) * HD;
#pragma unroll
            for (int j = 0; j < HD; ++j) w[j] = fmaf(s0, wr[j], w[j]);
#pragma unroll
            for (int j = 0; j < HD; ++j) w[j] = fmaf(s1, wr[HD + j], w[j]);
#pragma unroll
            for (int j = 0; j < HD; ++j) w[j] = fmaf(s2, wr[2 * HD + j], w[j]);
#pragma unroll
            for (int j = 0; j < HD; ++j) w[j] = fmaf(s3, wr[3 * HD + j], w[j]);
            hv = hn;
        }
    }

    // fold cosine cutoff; zero invalid edges so their atomics are no-ops
    float cw = 0.5f * (__cosf(ew[ec] * 0.31415926535897931f) + 1.0f);
    if (!valid) cw = 0.0f;

    sdst[wv][lane] = ei[(size_t)E + ec];
    ssrc[wv][lane] = ei[ec];

    const int c  = lane & 31;   // channel within half
    const int eh = lane & 32;   // which edge half this lane handles

    // ---- pass 0: channels [0,32); stash upper xs half in VGPRs ----
#pragma unroll
    for (int q = 0; q < HALF / 4; ++q)
        *(float4*)(hrow + 4 * q) = make_float4(w[4*q] * cw,     w[4*q + 1] * cw,
                                               w[4*q + 2] * cw, w[4*q + 3] * cw);
    __syncthreads();
    float xh[EPW / 2];   // statically indexed (full unroll) -> VGPRs
#pragma unroll
    for (int k = 0; k < EPW / 2; ++k) {
        int idx = k + eh;
        int dst = sdst[wv][idx];
        int src = ssrc[wv][idx];
        const float* xp = xs + (size_t)src * HD + c;
        float xlo = xp[0];
        xh[k] = xp[HALF];
        atomicAdd(&agg[(size_t)dst * HD + c], xlo * wbuf[wv][idx * PAD + c]);
    }
    __syncthreads();   // all lanes done reading before overwrite

    // ---- pass 1: channels [32,64); zero global reads ----
#pragma unroll
    for (int q = 0; q < HALF / 4; ++q)
        *(float4*)(hrow + 4 * q) = make_float4(w[HALF + 4*q] * cw,     w[HALF + 4*q + 1] * cw,
                                               w[HALF + 4*q + 2] * cw, w[HALF + 4*q + 3] * cw);
    __syncthreads();
#pragma unroll
    for (int k = 0; k < EPW / 2; ++k) {
        int idx = k + eh;
        int dst = sdst[wv][idx];
        atomicAdd(&agg[(size_t)dst * HD + HALF + c], xh[k] * wbuf[wv][idx * PAD + c]);
    }
}

// out = ssp(agg @ l2w + l2b) @ lin_w + lin_b. gridDim.y selects edge type.
__global__ void __launch_bounds__(256) out_kernel(
        const float* __restrict__ aggA, const float* __restrict__ aggB,
        const float* __restrict__ l2wA, const float* __restrict__ l2wB,
        const float* __restrict__ l2bA, const float* __restrict__ l2bB,
        const float* __restrict__ lw, const float* __restrict__ lb,
        float* __restrict__ outA, float* __restrict__ outB,
        int NA, int NB) {
    const int t = blockIdx.y;
    const float* agg = t ? aggB : aggA;
    const float* l2w = t ? l2wB : l2wA;
    const float* l2b = t ? l2bB : l2bA;
    float* out = t ? outB : outA;
    const int N = t ? NB : NA;

    int wv = threadIdx.x >> 6;
    int j  = threadIdx.x & 63;
    int n  = blockIdx.x * 4 + wv;
    __shared__ float buf[4][64];
    bool ok = n < N;
    if (ok) buf[wv][j] = agg[(size_t)n * HD + j];
    __syncthreads();
    float h = l2b[j];
#pragma unroll
    for (int g = 0; g < HD; ++g)
        h = fmaf(buf[wv][g], l2w[g * HD + j], h);
    h = ssp_f(h);
    __syncthreads();
    buf[wv][j] = h;
    __syncthreads();
    float o = lb[j];
#pragma unroll
    for (int g = 0; g < HD; ++g)
        o = fmaf(buf[wv][g], lw[g * HD + j], o);
    if (ok) out[(size_t)n * HD + j] = o;
}

extern "C" void kernel_launch(void* const* d_in, const int* in_sizes, int n_in,
                              void* d_out, int out_size, void* d_ws, size_t ws_size,
                              hipStream_t stream) {
    const float* x0   = (const float*)d_in[0];
    const float* x1   = (const float*)d_in[1];
    const int*   ei0  = (const int*)d_in[2];
    const int*   ei1  = (const int*)d_in[3];
    const float* ew0  = (const float*)d_in[4];
    const float* ew1  = (const float*)d_in[5];
    const float* ea0  = (const float*)d_in[6];
    const float* ea1  = (const float*)d_in[7];
    const float* mw1  = (const float*)d_in[8];
    const float* mb1  = (const float*)d_in[9];
    const float* mw2  = (const float*)d_in[10];
    const float* mb2  = (const float*)d_in[11];
    const float* l1w0 = (const float*)d_in[12];
    const float* l2w0 = (const float*)d_in[13];
    const float* l2b0 = (const float*)d_in[14];
    const float* l1w1 = (const float*)d_in[15];
    const float* l2w1 = (const float*)d_in[16];
    const float* l2b1 = (const float*)d_in[17];
    const float* lw   = (const float*)d_in[18];
    const float* lb   = (const float*)d_in[19];

    int N0 = in_sizes[0] / HD;
    int N1 = in_sizes[1] / HD;
    int E0 = in_sizes[4];
    int E1 = in_sizes[5];
    float* out = (float*)d_out;
    float* out0 = out;
    float* out1 = out + (size_t)N0 * HD;

    int Nmax = N0 > N1 ? N0 : N1;
    int Emax = E0 > E1 ? E0 : E1;
    int nodeBlocks = (Nmax + 3) / 4;
    int edgeBlocks = (Emax + WPB * EPW - 1) / (WPB * EPW);

    size_t needMerged = (size_t)(N0 + N1) * HD * 2 * sizeof(float);

    if (ws_size >= needMerged) {
        // merged path: 3 dispatches, gridDim.y = 2
        float* xs0  = (float*)d_ws;
        float* xs1  = xs0 + (size_t)N0 * HD;
        float* agg0 = xs1 + (size_t)N1 * HD;
        float* agg1 = agg0 + (size_t)N0 * HD;

        xs_kernel<<<dim3(nodeBlocks, 2), 256, 0, stream>>>(
            x0, x1, l1w0, l1w1, xs0, xs1, agg0, agg1, N0, N1);
        edge_kernel<<<dim3(edgeBlocks, 2), WPB * 64, 0, stream>>>(
            ea0, ea1, ew0, ew1, ei0, ei1, xs0, xs1, agg0, agg1,
            mw1, mb1, mw2, mb2, E0, E1);
        out_kernel<<<dim3(nodeBlocks, 2), 256, 0, stream>>>(
            agg0, agg1, l2w0, l2w1, l2b0, l2b1, lw, lb, out0, out1, N0, N1);
    } else {
        // fallback: sequential t-loop sharing one xs/agg buffer
        float* xs  = (float*)d_ws;
        float* agg = xs + (size_t)Nmax * HD;
        for (int t = 0; t < 2; ++t) {
            const float* x   = t ? x1 : x0;
            const int*   ei  = t ? ei1 : ei0;
            const float* ewp = t ? ew1 : ew0;
            const float* eap = t ? ea1 : ea0;
            const float* l1w = t ? l1w1 : l1w0;
            const float* l2w = t ? l2w1 : l2w0;
            const float* l2b = t ? l2b1 : l2b0;
            int N = t ? N1 : N0;
            int E = t ? E1 : E0;
            float* outp = t ? out1 : out0;
            int nb = (N + 3) / 4;
            int eb = (E + WPB * EPW - 1) / (WPB * EPW);
            xs_kernel<<<dim3(nb, 1), 256, 0, stream>>>(
                x, x, l1w, l1w, xs, xs, agg, agg, N, N);
            edge_kernel<<<dim3(eb, 1), WPB * 64, 0, stream>>>(
                eap, eap, ewp, ewp, ei, ei, xs, xs, agg, agg,
                mw1, mb1, mw2, mb2, E, E);
            out_kernel<<<dim3(nb, 1), 256, 0, stream>>>(
                agg, agg, l2w, l2w, l2b, l2b, lw, lb, outp, outp, N, N);
        }
    }
}